// Round 8
// baseline (66.746 us; speedup 1.0000x reference)
//
#include <hip/hip_runtime.h>

// Problem constants (fixed by setup_inputs): B=4, S=256, D=512, P=256
constexpr int B = 4;
constexpr int S = 256;
constexpr int D = 512;
constexpr int P = 256;
constexpr float NEG_INF = -1e9f;
constexpr float LOG2E = 1.4426950408889634f;
constexpr float C2 = 2.885390081777927f; // 2*log2(e):  exp2(C2*x) = e^{2x}

__device__ __forceinline__ float fast_exp2(float x) {
#if __has_builtin(__builtin_amdgcn_exp2f)
    return __builtin_amdgcn_exp2f(x);
#else
    return exp2f(x);
#endif
}

__device__ __forceinline__ float fast_rcp(float x) {
#if __has_builtin(__builtin_amdgcn_rcpf)
    return __builtin_amdgcn_rcpf(x);
#else
    return 1.0f / x;
#endif
}

// ---------------------------------------------------------------------------
// proj (R7 version): tile 16m x 64n, K-tile 64, 256 threads, 512 blocks
// (2 blocks/CU). out = exp2(C2 * acc).
// ---------------------------------------------------------------------------
__global__ __launch_bounds__(256)
void proj_kernel(const float* __restrict__ seq,
                 const float* __restrict__ W1, const float* __restrict__ W2,
                 float* __restrict__ Eq, float* __restrict__ EkT) {
    __shared__ float As[64][17]; // [k][m]
    __shared__ float Ws[64][68]; // [k][n]

    int bid0 = blockIdx.x;
    int bid = (bid0 & 7) * 64 + (bid0 >> 3); // XCD swizzle (512 = 8*64)

    const float* A;
    const float* Bp;
    float* out;
    if (bid < 256) { // Eq
        int mt = bid >> 2, nt = bid & 3;
        A = seq + (size_t)mt * 16 * D;
        Bp = W2 + (size_t)nt * 64 * D;
        out = Eq + (size_t)mt * 16 * 256 + nt * 64;
    } else {         // EkT
        int r = bid - 256;
        int b = r >> 6, t = r & 63;
        int mt = t >> 2, nt = t & 3;
        A = W1 + (size_t)mt * 16 * D;
        Bp = seq + ((size_t)b * S + nt * 64) * D;
        out = EkT + (size_t)b * P * S + (size_t)mt * 16 * 256 + nt * 64;
    }

    int tid = threadIdx.x;
    int tx = tid & 15, ty = tid >> 4;
    int arow = tid >> 4, akc = tid & 15;
    int brow = tid >> 2, bcg = tid & 3;
    const float* aptr = A + (size_t)arow * D + akc * 4;
    const float* bptr = Bp + (size_t)brow * D + bcg * 16;

    float4 a0, w0, w1, w2, w3;
    a0 = *(const float4*)(aptr);
    w0 = *(const float4*)(bptr);      w1 = *(const float4*)(bptr + 4);
    w2 = *(const float4*)(bptr + 8);  w3 = *(const float4*)(bptr + 12);

    float c0[4] = {0.f, 0.f, 0.f, 0.f};

    for (int kt = 0; kt < 8; kt++) {
        int ka = akc * 4;
        As[ka + 0][arow] = a0.x; As[ka + 1][arow] = a0.y;
        As[ka + 2][arow] = a0.z; As[ka + 3][arow] = a0.w;
        int kb = bcg * 16;
        Ws[kb + 0][brow] = w0.x;  Ws[kb + 1][brow] = w0.y;
        Ws[kb + 2][brow] = w0.z;  Ws[kb + 3][brow] = w0.w;
        Ws[kb + 4][brow] = w1.x;  Ws[kb + 5][brow] = w1.y;
        Ws[kb + 6][brow] = w1.z;  Ws[kb + 7][brow] = w1.w;
        Ws[kb + 8][brow] = w2.x;  Ws[kb + 9][brow] = w2.y;
        Ws[kb + 10][brow] = w2.z; Ws[kb + 11][brow] = w2.w;
        Ws[kb + 12][brow] = w3.x; Ws[kb + 13][brow] = w3.y;
        Ws[kb + 14][brow] = w3.z; Ws[kb + 15][brow] = w3.w;
        __syncthreads();
        if (kt < 7) {
            const float* ap = aptr + (kt + 1) * 64;
            const float* bp = bptr + (kt + 1) * 64;
            a0 = *(const float4*)(ap);
            w0 = *(const float4*)(bp);     w1 = *(const float4*)(bp + 4);
            w2 = *(const float4*)(bp + 8); w3 = *(const float4*)(bp + 12);
        }
#pragma unroll 8
        for (int k = 0; k < 64; k++) {
            float av = As[k][ty];
            float4 wv = *(const float4*)&Ws[k][tx * 4];
            c0[0] = fmaf(av, wv.x, c0[0]);
            c0[1] = fmaf(av, wv.y, c0[1]);
            c0[2] = fmaf(av, wv.z, c0[2]);
            c0[3] = fmaf(av, wv.w, c0[3]);
        }
        __syncthreads();
    }
    float4 o0 = {fast_exp2(c0[0] * C2), fast_exp2(c0[1] * C2),
                 fast_exp2(c0[2] * C2), fast_exp2(c0[3] * C2)};
    *(float4*)&out[(size_t)ty * 256 + tx * 4] = o0;
}

// ---------------------------------------------------------------------------
// score v8: block = (b, 4 queries), 256 threads, 256 blocks.
// NO LDS staging of Ek, NO barriers in the hot loop: wave w owns p-quarter
// [64w, 64w+64); lane l owns j-quad {4l..4l+3}. Per p-step one coalesced
// float4 global load (L2-resident EkT), Eq/v via LDS broadcast. 64
// independent loads per wave, 8-deep unroll -> latency hidden by MLP.
//  score(i,j) = const + sum_p (-2 v[p]) * rcp(Eq[i,p]*EkT[p,j] + 1)
// ---------------------------------------------------------------------------
__global__ __launch_bounds__(256)
void score_kernel(const float* __restrict__ EkT, const float* __restrict__ Eq,
                  const float* __restrict__ v, const float* __restrict__ mask,
                  float* __restrict__ wout) {
    __shared__ float Eqs[4][P];       // 4 KB
    __shared__ float vsm[P];          // 1 KB  (-2*v)
    __shared__ float part[4][4][S];   // 16 KB [w][q][j]
    __shared__ float redm[4][4], reds[4][4];

    int bid0 = blockIdx.x;
    int bid = (bid0 & 7) * 32 + (bid0 >> 3); // XCD swizzle; b = bid>>6 -> XCD pair
    int b = bid >> 6;
    int i0 = (bid & 63) * 4;
    int tid = threadIdx.x;
    int w = tid >> 6, l = tid & 63;

    // stage Eq rows (4 x 256 contiguous) and v' = -2v
    {
        const float2* src = (const float2*)(Eq + ((size_t)b * S + i0) * P);
        ((float2*)Eqs)[tid] = src[tid];
        ((float2*)Eqs)[tid + 256] = src[tid + 256];
        if (tid < 128) {
            float2 vv = ((const float2*)v)[tid];
            ((float2*)vsm)[tid] = make_float2(-2.f * vv.x, -2.f * vv.y);
        }
    }
    __syncthreads();

    // phase 1: no barriers, direct global Ek loads
    {
        int p0 = w * 64;
        const float* ekp = EkT + (size_t)b * P * S + (size_t)p0 * S + l * 4;
        float4 a0 = {0.f, 0.f, 0.f, 0.f};
        float4 a1 = a0, a2 = a0, a3 = a0;
#pragma unroll 8
        for (int pp = 0; pp < 64; ++pp) {
            float4 ek = *(const float4*)(ekp + (size_t)pp * S);
            int p = p0 + pp;
            float vv = vsm[p];
            float q0 = Eqs[0][p], q1 = Eqs[1][p];
            float q2 = Eqs[2][p], q3 = Eqs[3][p];
            a0.x = fmaf(vv, fast_rcp(fmaf(ek.x, q0, 1.f)), a0.x);
            a0.y = fmaf(vv, fast_rcp(fmaf(ek.y, q0, 1.f)), a0.y);
            a0.z = fmaf(vv, fast_rcp(fmaf(ek.z, q0, 1.f)), a0.z);
            a0.w = fmaf(vv, fast_rcp(fmaf(ek.w, q0, 1.f)), a0.w);
            a1.x = fmaf(vv, fast_rcp(fmaf(ek.x, q1, 1.f)), a1.x);
            a1.y = fmaf(vv, fast_rcp(fmaf(ek.y, q1, 1.f)), a1.y);
            a1.z = fmaf(vv, fast_rcp(fmaf(ek.z, q1, 1.f)), a1.z);
            a1.w = fmaf(vv, fast_rcp(fmaf(ek.w, q1, 1.f)), a1.w);
            a2.x = fmaf(vv, fast_rcp(fmaf(ek.x, q2, 1.f)), a2.x);
            a2.y = fmaf(vv, fast_rcp(fmaf(ek.y, q2, 1.f)), a2.y);
            a2.z = fmaf(vv, fast_rcp(fmaf(ek.z, q2, 1.f)), a2.z);
            a2.w = fmaf(vv, fast_rcp(fmaf(ek.w, q2, 1.f)), a2.w);
            a3.x = fmaf(vv, fast_rcp(fmaf(ek.x, q3, 1.f)), a3.x);
            a3.y = fmaf(vv, fast_rcp(fmaf(ek.y, q3, 1.f)), a3.y);
            a3.z = fmaf(vv, fast_rcp(fmaf(ek.z, q3, 1.f)), a3.z);
            a3.w = fmaf(vv, fast_rcp(fmaf(ek.w, q3, 1.f)), a3.w);
        }
        *(float4*)&part[w][0][l * 4] = a0;
        *(float4*)&part[w][1][l * 4] = a1;
        *(float4*)&part[w][2][l * 4] = a2;
        *(float4*)&part[w][3][l * 4] = a3;
    }
    __syncthreads();

    // phase 2: softmax over keys (all 256 threads, thread = j)
    int j = tid;
    int lane = tid & 63, wid = tid >> 6;
    float km = mask[(size_t)b * S + j];
    float s[4], e[4];
#pragma unroll
    for (int q = 0; q < 4; q++) {
        float sv = (part[0][q][j] + part[1][q][j]) +
                   (part[2][q][j] + part[3][q][j]);
        s[q] = (km > 0.f) ? sv : NEG_INF;
        float mm = s[q];
#pragma unroll
        for (int off = 32; off >= 1; off >>= 1)
            mm = fmaxf(mm, __shfl_xor(mm, off, 64));
        if (lane == 0) redm[q][wid] = mm;
    }
    __syncthreads();
#pragma unroll
    for (int q = 0; q < 4; q++) {
        float mm = fmaxf(fmaxf(redm[q][0], redm[q][1]),
                         fmaxf(redm[q][2], redm[q][3]));
        float ee = fast_exp2((s[q] - mm) * LOG2E);
        e[q] = ee;
        float ss = ee;
#pragma unroll
        for (int off = 32; off >= 1; off >>= 1)
            ss += __shfl_xor(ss, off, 64);
        if (lane == 0) reds[q][wid] = ss;
    }
    __syncthreads();
#pragma unroll
    for (int q = 0; q < 4; q++) {
        float ssum = (reds[q][0] + reds[q][1]) + (reds[q][2] + reds[q][3]);
        float qm = mask[(size_t)b * S + i0 + q];
        float wgt = e[q] * fast_rcp(ssum) * qm;
        wout[((size_t)b * S + i0 + q) * S + j] = wgt;
    }
}

// ---------------------------------------------------------------------------
// attn GEMM (R7 version): attn[b] = wout[b] @ seq[b]. tile 16i x 64d, K=256.
// 512 blocks (2/CU), 256 threads, reg prefetch. wout carries the query mask.
// ---------------------------------------------------------------------------
__global__ __launch_bounds__(256)
void attn_kernel(const float* __restrict__ wts, const float* __restrict__ seq,
                 float* __restrict__ attn) {
    __shared__ float As[64][17]; // [k][m]  (weights, transposed)
    __shared__ float Ws[64][68]; // [k][n]  (seq rows, natural layout)

    int bid0 = blockIdx.x;
    int bid = (bid0 & 7) * 64 + (bid0 >> 3); // XCD swizzle (512 = 8*64)
    int b = bid >> 7;
    int t = bid & 127;
    int i0 = (t >> 3) * 16;
    int d0 = (t & 7) * 64;

    int tid = threadIdx.x;
    int tx = tid & 15, ty = tid >> 4;
    int arow = tid >> 4, akc = tid & 15;
    int brow = tid >> 2, bcg = tid & 3;
    const float* aptr = wts + ((size_t)b * S + i0 + arow) * S + akc * 4;
    const float* bptr = seq + ((size_t)b * S + brow) * D + d0 + bcg * 16;

    float4 a0, w0, w1, w2, w3;
    a0 = *(const float4*)(aptr);
    w0 = *(const float4*)(bptr);      w1 = *(const float4*)(bptr + 4);
    w2 = *(const float4*)(bptr + 8);  w3 = *(const float4*)(bptr + 12);

    float c0[4] = {0.f, 0.f, 0.f, 0.f};

    for (int kt = 0; kt < 4; kt++) {
        int ka = akc * 4;
        As[ka + 0][arow] = a0.x; As[ka + 1][arow] = a0.y;
        As[ka + 2][arow] = a0.z; As[ka + 3][arow] = a0.w;
        int kb = bcg * 16;
        *(float4*)&Ws[brow][kb + 0] = w0;   // brow is k here
        *(float4*)&Ws[brow][kb + 4] = w1;
        *(float4*)&Ws[brow][kb + 8] = w2;
        *(float4*)&Ws[brow][kb + 12] = w3;
        __syncthreads();
        if (kt < 3) {
            const float* ap = aptr + (kt + 1) * 64;
            const float* bp = bptr + (size_t)(kt + 1) * 64 * D;
            a0 = *(const float4*)(ap);
            w0 = *(const float4*)(bp);     w1 = *(const float4*)(bp + 4);
            w2 = *(const float4*)(bp + 8); w3 = *(const float4*)(bp + 12);
        }
#pragma unroll 8
        for (int k = 0; k < 64; k++) {
            float av = As[k][ty];
            float4 wv = *(const float4*)&Ws[k][tx * 4];
            c0[0] = fmaf(av, wv.x, c0[0]);
            c0[1] = fmaf(av, wv.y, c0[1]);
            c0[2] = fmaf(av, wv.z, c0[2]);
            c0[3] = fmaf(av, wv.w, c0[3]);
        }
        __syncthreads();
    }
    *(float4*)&attn[((size_t)b * S + i0 + ty) * D + d0 + tx * 4] =
        make_float4(c0[0], c0[1], c0[2], c0[3]);
}

// ---------------------------------------------------------------------------
extern "C" void kernel_launch(void* const* d_in, const int* in_sizes, int n_in,
                              void* d_out, int out_size, void* d_ws, size_t ws_size,
                              hipStream_t stream) {
    const float* seq  = (const float*)d_in[0];
    const float* mask = (const float*)d_in[1];
    const float* W1   = (const float*)d_in[2];
    const float* W2   = (const float*)d_in[3];
    const float* v    = (const float*)d_in[4];

    float* attn = (float*)d_out;                 // [B,S,D]
    float* wout = attn + (size_t)B * S * D;      // [B,S,S]

    float* Eq  = (float*)d_ws;                   // [B*S, P]  = exp2(C2*pq)
    float* EkT = Eq + (size_t)B * S * P;         // [B, P, S] = exp2(C2*pk)^T

    proj_kernel<<<512, 256, 0, stream>>>(seq, W1, W2, Eq, EkT);
    score_kernel<<<B * (S / 4), 256, 0, stream>>>(EkT, Eq, v, mask, wout);
    attn_kernel<<<512, 256, 0, stream>>>(wout, seq, attn);
}